// Round 3
// baseline (56.071 us; speedup 1.0000x reference)
//
#include <hip/hip_runtime.h>

namespace {
constexpr int B = 4, C = 64, H = 128, W = 128, O = 64, KK = 9;
constexpr int THREADS = 256;
constexpr int WF_ELEMS = KK * 2 * 4 * 64 * 8;                   // 36864
constexpr size_t XT_BYTES = (size_t)B * H * W * C * 2;          // 16,777,216
constexpr size_t WF_BYTES = (size_t)WF_ELEMS * 2;               // 73,728
constexpr size_t WS_NEED  = XT_BYTES + WF_BYTES;
}

typedef float  f32x4 __attribute__((ext_vector_type(4)));
typedef short  s16x8 __attribute__((ext_vector_type(8)));

__device__ __forceinline__ float lo16(unsigned u) { return __uint_as_float(u << 16); }
__device__ __forceinline__ float hi16(unsigned u) { return __uint_as_float(u & 0xFFFF0000u); }
__device__ __forceinline__ unsigned bpack(float a, float b) {   // RNE bf16 pair
  unsigned ua = __float_as_uint(a); ua += 0x7FFFu + ((ua >> 16) & 1u);
  unsigned ub = __float_as_uint(b); ub += 0x7FFFu + ((ub >> 16) & 1u);
  return (ua >> 16) | (ub & 0xFFFF0000u);
}

// ---------- prep: x[b][c][h][w] f32 -> x_t[b][h][w][c] bf16,  + weight->frag ----------
__global__ __launch_bounds__(THREADS)
void prep_fused(const float* __restrict__ x, const float* __restrict__ wgt,
                unsigned* __restrict__ xt_u32, unsigned short* __restrict__ wf) {
  __shared__ float st[64][65];
  const int t = threadIdx.x;

  // weight -> bf16 A-fragment order (first 144 blocks, one elem/thread)
  // o = mt*16 + (lane&15), c = ks*32 + (lane>>4)*8 + e
  const int gid = blockIdx.x * THREADS + t;
  if (gid < WF_ELEMS) {
    const int e = gid & 7, lane = (gid >> 3) & 63, mt = (gid >> 9) & 3;
    const int ks = (gid >> 11) & 1, tap = gid >> 12;
    const int o = mt * 16 + (lane & 15);
    const int c = ks * 32 + ((lane >> 4) << 3) + e;
    unsigned u = __float_as_uint(wgt[(size_t)o * (C * KK) + c * KK + tap]);
    u += 0x7FFFu + ((u >> 16) & 1u);
    wf[gid] = (unsigned short)(u >> 16);
  }

  const int half = blockIdx.x & 1, h = (blockIdx.x >> 1) & 127, b = blockIdx.x >> 8;
  const int w0 = half * 64;
#pragma unroll
  for (int it = 0; it < 16; ++it) {
    const int w = t & 63, c = it * 4 + (t >> 6);
    st[w][c] = x[((size_t)(b * C + c) * H + h) * W + w0 + w];
  }
  __syncthreads();
#pragma unroll
  for (int it = 0; it < 8; ++it) {
    const int idx = it * THREADS + t;
    const int w = idx >> 5, c2 = (idx & 31) * 2;
    xt_u32[(size_t)(((b * H + h) * W) + w0 + w) * 32 + (c2 >> 1)] = bpack(st[w][c2], st[w][c2 + 1]);
  }
}

// ---------- main: fused deform-sample + MFMA, B-fragment built in registers ----------
__global__ __launch_bounds__(THREADS, 4)
void deform_mfma(const float* __restrict__ offs, const char* __restrict__ xt,
                 const char* __restrict__ wf, float* __restrict__ out) {
  __shared__ float s_p[4][KK][16][8];   // per-wave sampling params (18.4 KB total)

  const int t = threadIdx.x, l = t & 63, wid = t >> 6;
  const int half = blockIdx.x & 1, h = (blockIdx.x >> 1) & 127, b = blockIdx.x >> 8;
  const int wbase = half * 64 + wid * 16;        // wave's first pixel (global w)

  // --- sampling params: this wave's 16 pixels x 9 taps ---
#pragma unroll
  for (int it = 0; it < 3; ++it) {
    const int item = it * 64 + l;
    if (item < KK * 16) {
      const int tap = item >> 4, pix = item & 15;
      const int ki = tap / 3, kj = tap - ki * 3;
      const int w = wbase + pix;
      const float* ob = offs + ((size_t)b * (2 * KK) + 2 * tap) * (H * W) + h * W + w;
      const float oi = ob[0], oj = ob[H * W];
      const float ci = oi + (float)(h + ki - 1);
      const float cj = oj + (float)(w + kj - 1);
      const float fli = floorf(ci), flj = floorf(cj);
      const int i0 = (int)fli, j0 = (int)flj, i1 = i0 + 1, j1 = j0 + 1;
      const float fi = ci - fli, fj = cj - flj, gi = 1.f - fi, gj = 1.f - fj;
      const bool bi0 = (unsigned)i0 < (unsigned)H, bi1 = (unsigned)i1 < (unsigned)H;
      const bool bj0 = (unsigned)j0 < (unsigned)W, bj1 = (unsigned)j1 < (unsigned)W;
      const int ic0 = min(max(i0, 0), H - 1), ic1 = min(max(i1, 0), H - 1);
      const int jc0 = min(max(j0, 0), W - 1), jc1 = min(max(j1, 0), W - 1);
      float* sp = &s_p[wid][tap][pix][0];
      sp[0] = gi * gj * (float)(bi0 && bj0);
      sp[1] = gi * fj * (float)(bi0 && bj1);
      sp[2] = fi * gj * (float)(bi1 && bj0);
      sp[3] = fi * fj * (float)(bi1 && bj1);
      sp[4] = __int_as_float(((b * H + ic0) * W + jc0) << 7);   // byte addr in x_t
      sp[5] = __int_as_float(((b * H + ic0) * W + jc1) << 7);
      sp[6] = __int_as_float(((b * H + ic1) * W + jc0) << 7);
      sp[7] = __int_as_float(((b * H + ic1) * W + jc1) << 7);
    }
  }

  const int pix = l & 15;
  const int cb  = (l >> 4) << 4;   // lane's channel-byte offset within 128B pixel record

  f32x4 acc[4];
#pragma unroll
  for (int mt = 0; mt < 4; ++mt) acc[mt] = (f32x4)0.f;

  // G[2c+ks] = corner c, k-half ks : 16B = 8 channels for this lane's fragment slot
#define ISSUE_TAP(TAP, G) do {                                              \
    const float4 af_ = *(const float4*)&s_p[wid][(TAP)][pix][4];            \
    const char* a0_ = xt + __float_as_int(af_.x) + cb;                      \
    const char* a1_ = xt + __float_as_int(af_.y) + cb;                      \
    const char* a2_ = xt + __float_as_int(af_.z) + cb;                      \
    const char* a3_ = xt + __float_as_int(af_.w) + cb;                      \
    G[0] = *(const uint4*)a0_;  G[1] = *(const uint4*)(a0_ + 64);           \
    G[2] = *(const uint4*)a1_;  G[3] = *(const uint4*)(a1_ + 64);           \
    G[4] = *(const uint4*)a2_;  G[5] = *(const uint4*)(a2_ + 64);           \
    G[6] = *(const uint4*)a3_;  G[7] = *(const uint4*)(a3_ + 64);           \
  } while (0)

#define LERPW(c0_, c1_, c2_, c3_) bpack(                                     \
    wv.x * lo16(c0_) + wv.y * lo16(c1_) + wv.z * lo16(c2_) + wv.w * lo16(c3_), \
    wv.x * hi16(c0_) + wv.y * hi16(c1_) + wv.z * hi16(c2_) + wv.w * hi16(c3_))

  uint4 gA[8], gB[8];
  ISSUE_TAP(0, gA);

#pragma unroll
  for (int tap = 0; tap < KK; ++tap) {
    // static buffer alternation (rule #20: indices resolve at compile time)
    uint4* gc = (tap & 1) ? gB : gA;
    uint4* gn = (tap & 1) ? gA : gB;
    if (tap + 1 < KK) ISSUE_TAP(tap + 1, gn);

    const float4 wv = *(const float4*)&s_p[wid][tap][pix][0];
    uint4 r0, r1;
    r0.x = LERPW(gc[0].x, gc[2].x, gc[4].x, gc[6].x);
    r0.y = LERPW(gc[0].y, gc[2].y, gc[4].y, gc[6].y);
    r0.z = LERPW(gc[0].z, gc[2].z, gc[4].z, gc[6].z);
    r0.w = LERPW(gc[0].w, gc[2].w, gc[4].w, gc[6].w);
    r1.x = LERPW(gc[1].x, gc[3].x, gc[5].x, gc[7].x);
    r1.y = LERPW(gc[1].y, gc[3].y, gc[5].y, gc[7].y);
    r1.z = LERPW(gc[1].z, gc[3].z, gc[5].z, gc[7].z);
    r1.w = LERPW(gc[1].w, gc[3].w, gc[5].w, gc[7].w);
    const s16x8 b0 = *(const s16x8*)&r0;
    const s16x8 b1 = *(const s16x8*)&r1;

#pragma unroll
    for (int mt = 0; mt < 4; ++mt) {
      const s16x8 a0 = *(const s16x8*)(wf + ((((tap * 2 + 0) * 4 + mt) * 64 + l) << 4));
      acc[mt] = __builtin_amdgcn_mfma_f32_16x16x32_bf16(a0, b0, acc[mt], 0, 0, 0);
    }
#pragma unroll
    for (int mt = 0; mt < 4; ++mt) {
      const s16x8 a1 = *(const s16x8*)(wf + ((((tap * 2 + 1) * 4 + mt) * 64 + l) << 4));
      acc[mt] = __builtin_amdgcn_mfma_f32_16x16x32_bf16(a1, b1, acc[mt], 0, 0, 0);
    }
  }
#undef ISSUE_TAP
#undef LERPW

  // --- epilogue: coalesced stores ---
#pragma unroll
  for (int mt = 0; mt < 4; ++mt)
#pragma unroll
    for (int j = 0; j < 4; ++j) {
      const int o = mt * 16 + ((l >> 4) << 2) + j;
      out[((size_t)(b * O + o) * H + h) * W + wbase + pix] = acc[mt][j];
    }
}

// ---------- fallback (round-1 kernel, used only if ws too small) ----------
namespace fb {
constexpr int WT = 32, CH = 16, NCHUNK = 4, KC = 144, WPAD = 68;
}
__global__ __launch_bounds__(THREADS, 2)
void deform_conv_fused(const float* __restrict__ x, const float* __restrict__ offs,
                       const float* __restrict__ wgt, float* __restrict__ out) {
  using namespace fb;
  __shared__ int   s_i0[KK][WT];
  __shared__ int   s_j0[KK][WT];
  __shared__ float s_fi[KK][WT];
  __shared__ float s_fj[KK][WT];
  __shared__ float s_w[KC][WPAD];
  __shared__ float s_m[KC][WT + 1];
  const int t = threadIdx.x;
  const int nwt = W / WT;
  const int wt = blockIdx.x % nwt, h = (blockIdx.x / nwt) % H, b = blockIdx.x / (nwt * H);
  const int w0 = wt * WT;
  for (int idx = t; idx < KK * WT; idx += THREADS) {
    const int k = idx / WT, p = idx % WT, w = w0 + p;
    const float oi = offs[(((size_t)b * (2 * KK) + 2 * k) * H + h) * W + w];
    const float oj = offs[(((size_t)b * (2 * KK) + 2 * k + 1) * H + h) * W + w];
    const float ci = oi + (float)(h + (k / 3) - 1), cj = oj + (float)(w + (k % 3) - 1);
    const float fli = floorf(ci), flj = floorf(cj);
    s_i0[k][p] = (int)fli; s_j0[k][p] = (int)flj;
    s_fi[k][p] = ci - fli; s_fj[k][p] = cj - flj;
  }
  float acc[8];
#pragma unroll
  for (int i = 0; i < 8; ++i) acc[i] = 0.f;
  const int p = t & (WT - 1), ob = (t >> 5) * 8;
  for (int cc = 0; cc < NCHUNK; ++cc) {
    const int c0 = cc * CH;
    __syncthreads();
    for (int idx = t; idx < O * KC; idx += THREADS)
      s_w[idx % KC][idx / KC] = wgt[(size_t)(idx / KC) * (C * KK) + (size_t)c0 * KK + idx % KC];
    for (int idx = t; idx < CH * KK * WT; idx += THREADS) {
      const int pp = idx & (WT - 1), rest = idx >> 5, k = rest % KK, cl = rest / KK;
      const int i0 = s_i0[k][pp], j0 = s_j0[k][pp], i1 = i0 + 1, j1 = j0 + 1;
      const float fi = s_fi[k][pp], fj = s_fj[k][pp];
      const float* xb = x + (size_t)(b * C + c0 + cl) * H * W;
      const float v00 = ((unsigned)i0 < (unsigned)H && (unsigned)j0 < (unsigned)W) ? xb[i0 * W + j0] : 0.f;
      const float v01 = ((unsigned)i0 < (unsigned)H && (unsigned)j1 < (unsigned)W) ? xb[i0 * W + j1] : 0.f;
      const float v10 = ((unsigned)i1 < (unsigned)H && (unsigned)j0 < (unsigned)W) ? xb[i1 * W + j0] : 0.f;
      const float v11 = ((unsigned)i1 < (unsigned)H && (unsigned)j1 < (unsigned)W) ? xb[i1 * W + j1] : 0.f;
      const float top = v00 + fj * (v01 - v00), bot = v10 + fj * (v11 - v10);
      s_m[cl * KK + k][pp] = top + fi * (bot - top);
    }
    __syncthreads();
#pragma unroll 4
    for (int k = 0; k < KC; ++k) {
      const float a = s_m[k][p];
      const float4 wv0 = *reinterpret_cast<const float4*>(&s_w[k][ob]);
      const float4 wv1 = *reinterpret_cast<const float4*>(&s_w[k][ob + 4]);
      acc[0] += a * wv0.x; acc[1] += a * wv0.y; acc[2] += a * wv0.z; acc[3] += a * wv0.w;
      acc[4] += a * wv1.x; acc[5] += a * wv1.y; acc[6] += a * wv1.z; acc[7] += a * wv1.w;
    }
  }
#pragma unroll
  for (int i = 0; i < 8; ++i)
    out[(((size_t)b * O + ob + i) * H + h) * W + w0 + p] = acc[i];
}

extern "C" void kernel_launch(void* const* d_in, const int* in_sizes, int n_in,
                              void* d_out, int out_size, void* d_ws, size_t ws_size,
                              hipStream_t stream) {
  const float* x    = (const float*)d_in[0];
  const float* offs = (const float*)d_in[1];
  const float* wgt  = (const float*)d_in[2];
  float* out = (float*)d_out;

  if (ws_size < WS_NEED) {   // fallback: round-1 kernel
    deform_conv_fused<<<B * H * (W / 32), THREADS, 0, stream>>>(x, offs, wgt, out);
    return;
  }
  char* xt = (char*)d_ws;
  unsigned short* wf = (unsigned short*)(xt + XT_BYTES);

  prep_fused<<<B * H * 2, THREADS, 0, stream>>>(x, wgt, (unsigned*)xt, wf);
  deform_mfma<<<B * H * 2, THREADS, 0, stream>>>(offs, xt, (const char*)wf, out);
}

// Round 4
// 37.319 us; speedup vs baseline: 1.5025x; 1.5025x over previous
//
#include <hip/hip_runtime.h>

namespace {
constexpr int B = 4, C = 64, H = 128, W = 128, O = 64, KK = 9;
constexpr int THREADS = 256;
constexpr int WF_ELEMS = KK * 2 * 4 * 64 * 8;                   // 36864
constexpr size_t XT_BYTES = (size_t)B * H * W * C * 2;          // 16,777,216
constexpr size_t WF_BYTES = (size_t)WF_ELEMS * 2;               // 73,728
constexpr size_t WS_NEED  = XT_BYTES + WF_BYTES;
}

typedef float  f32x4 __attribute__((ext_vector_type(4)));
typedef short  s16x8 __attribute__((ext_vector_type(8)));

__device__ __forceinline__ float lo16(unsigned u) { return __uint_as_float(u << 16); }
__device__ __forceinline__ float hi16(unsigned u) { return __uint_as_float(u & 0xFFFF0000u); }
__device__ __forceinline__ unsigned bpack(float a, float b) {   // RNE bf16 pair
  unsigned ua = __float_as_uint(a); ua += 0x7FFFu + ((ua >> 16) & 1u);
  unsigned ub = __float_as_uint(b); ub += 0x7FFFu + ((ub >> 16) & 1u);
  return (ua >> 16) | (ub & 0xFFFF0000u);
}

// ---------- prep: x[b][c][h][w] f32 -> x_t[b][h][w][c] bf16,  + weight->frag ----------
__global__ __launch_bounds__(THREADS)
void prep_fused(const float* __restrict__ x, const float* __restrict__ wgt,
                unsigned* __restrict__ xt_u32, unsigned short* __restrict__ wf) {
  __shared__ float st[64][65];
  const int t = threadIdx.x;

  // weight -> bf16 A-fragment order (first 144 blocks, one elem/thread)
  // o = mt*16 + (lane&15), c = ks*32 + (lane>>4)*8 + e
  const int gid = blockIdx.x * THREADS + t;
  if (gid < WF_ELEMS) {
    const int e = gid & 7, lane = (gid >> 3) & 63, mt = (gid >> 9) & 3;
    const int ks = (gid >> 11) & 1, tap = gid >> 12;
    const int o = mt * 16 + (lane & 15);
    const int c = ks * 32 + ((lane >> 4) << 3) + e;
    unsigned u = __float_as_uint(wgt[(size_t)o * (C * KK) + c * KK + tap]);
    u += 0x7FFFu + ((u >> 16) & 1u);
    wf[gid] = (unsigned short)(u >> 16);
  }

  const int half = blockIdx.x & 1, h = (blockIdx.x >> 1) & 127, b = blockIdx.x >> 8;
  const int w0 = half * 64;
#pragma unroll
  for (int it = 0; it < 16; ++it) {
    const int w = t & 63, c = it * 4 + (t >> 6);
    st[w][c] = x[((size_t)(b * C + c) * H + h) * W + w0 + w];
  }
  __syncthreads();
#pragma unroll
  for (int it = 0; it < 8; ++it) {
    const int idx = it * THREADS + t;
    const int w = idx >> 5, c2 = (idx & 31) * 2;
    xt_u32[(size_t)(((b * H + h) * W) + w0 + w) * 32 + (c2 >> 1)] = bpack(st[w][c2], st[w][c2 + 1]);
  }
}

// ---------- main: fused deform-sample + LDS-staged MFMA, 1-tap-ahead pipeline ----------
__global__ __launch_bounds__(THREADS) __attribute__((amdgpu_waves_per_eu(4, 4)))
void deform_mfma(const float* __restrict__ offs, const char* __restrict__ xt,
                 const char* __restrict__ wf, float* __restrict__ out) {
  __shared__ float          s_p[4][KK][16][8];   // sampling params (18.4 KB)
  __shared__ unsigned short s_m[64 * 64];        // [block pix][c] bf16, swizzled (8 KB)

  const int t = threadIdx.x, l = t & 63, wid = t >> 6;
  const int half = blockIdx.x & 1, h = (blockIdx.x >> 1) & 127, b = blockIdx.x >> 8;
  const int wbase = half * 64 + wid * 16;        // wave's first pixel (global w)

  // --- sampling params: this wave's 16 pixels x 9 taps (wave-private, no barrier) ---
#pragma unroll
  for (int it = 0; it < 3; ++it) {
    const int item = it * 64 + l;
    if (item < KK * 16) {
      const int tap = item >> 4, pix = item & 15;
      const int ki = tap / 3, kj = tap - ki * 3;
      const int w = wbase + pix;
      const float* ob = offs + ((size_t)b * (2 * KK) + 2 * tap) * (H * W) + h * W + w;
      const float oi = ob[0], oj = ob[H * W];
      const float ci = oi + (float)(h + ki - 1);
      const float cj = oj + (float)(w + kj - 1);
      const float fli = floorf(ci), flj = floorf(cj);
      const int i0 = (int)fli, j0 = (int)flj, i1 = i0 + 1, j1 = j0 + 1;
      const float fi = ci - fli, fj = cj - flj, gi = 1.f - fi, gj = 1.f - fj;
      const bool bi0 = (unsigned)i0 < (unsigned)H, bi1 = (unsigned)i1 < (unsigned)H;
      const bool bj0 = (unsigned)j0 < (unsigned)W, bj1 = (unsigned)j1 < (unsigned)W;
      const int ic0 = min(max(i0, 0), H - 1), ic1 = min(max(i1, 0), H - 1);
      const int jc0 = min(max(j0, 0), W - 1), jc1 = min(max(j1, 0), W - 1);
      float* sp = &s_p[wid][tap][pix][0];
      sp[0] = gi * gj * (float)(bi0 && bj0);
      sp[1] = gi * fj * (float)(bi0 && bj1);
      sp[2] = fi * gj * (float)(bi1 && bj0);
      sp[3] = fi * fj * (float)(bi1 && bj1);
      sp[4] = __int_as_float(((b * H + ic0) * W + jc0) << 7);   // byte addr in x_t
      sp[5] = __int_as_float(((b * H + ic0) * W + jc1) << 7);
      sp[6] = __int_as_float(((b * H + ic1) * W + jc0) << 7);
      sp[7] = __int_as_float(((b * H + ic1) * W + jc1) << 7);
    }
  }

  // gather lane map: 8 lanes (oct 0..7) cover one pixel-corner's 128B contiguously
  const int pix8 = l >> 3;          // 0..7 : pixel within iter-group
  const int oct  = l & 7;           // 16B chunk within 128B pixel record
  const int cb   = oct << 4;

  // LDS write target (swizzled): row = wid*16 + iter*8 + pix8, slot = oct ^ (row&7)
  char* smb = (char*)s_m;
  const int wbyte0 = ((wid * 16 + pix8) << 7) + ((oct ^ pix8) << 4);  // iter0; iter1 = +1024

  // MFMA b-frag read addrs (tap-invariant): row rr, slot (ks*4 + (l>>4)) ^ (rr&7)
  const int rr  = wid * 16 + (l & 15);
  const int rd0 = (rr << 7) + ((((0 << 2) + (l >> 4)) ^ (l & 7)) << 4);
  const int rd1 = (rr << 7) + ((((1 << 2) + (l >> 4)) ^ (l & 7)) << 4);

  f32x4 acc[4];
#pragma unroll
  for (int mt = 0; mt < 4; ++mt) acc[mt] = (f32x4)0.f;

  // G[0..3] = 4 corners of pixel pix8 ; G[4..7] = 4 corners of pixel 8+pix8
#define GATHER(TAP, G) do {                                                  \
    const float4 af0_ = *(const float4*)&s_p[wid][(TAP)][pix8][4];           \
    const float4 af1_ = *(const float4*)&s_p[wid][(TAP)][8 + pix8][4];       \
    G[0] = *(const uint4*)(xt + __float_as_int(af0_.x) + cb);                \
    G[1] = *(const uint4*)(xt + __float_as_int(af0_.y) + cb);                \
    G[2] = *(const uint4*)(xt + __float_as_int(af0_.z) + cb);                \
    G[3] = *(const uint4*)(xt + __float_as_int(af0_.w) + cb);                \
    G[4] = *(const uint4*)(xt + __float_as_int(af1_.x) + cb);                \
    G[5] = *(const uint4*)(xt + __float_as_int(af1_.y) + cb);                \
    G[6] = *(const uint4*)(xt + __float_as_int(af1_.z) + cb);                \
    G[7] = *(const uint4*)(xt + __float_as_int(af1_.w) + cb);                \
  } while (0)

#define LERPW(wv, c0_, c1_, c2_, c3_) bpack(                                   \
    wv.x * lo16(c0_) + wv.y * lo16(c1_) + wv.z * lo16(c2_) + wv.w * lo16(c3_), \
    wv.x * hi16(c0_) + wv.y * hi16(c1_) + wv.z * hi16(c2_) + wv.w * hi16(c3_))

  uint4 gA[8], gB[8];
  GATHER(0, gA);

#pragma unroll
  for (int tap = 0; tap < KK; ++tap) {
    uint4* gc = (tap & 1) ? gB : gA;   // static under full unroll (rule #20)
    uint4* gn = (tap & 1) ? gA : gB;
    if (tap + 1 < KK) GATHER(tap + 1, gn);   // prefetch next tap's corners

    // --- lerp current tap, write swizzled LDS ---
    const float4 wv0 = *(const float4*)&s_p[wid][tap][pix8][0];
    const float4 wv1 = *(const float4*)&s_p[wid][tap][8 + pix8][0];
    uint4 r0, r1;
    r0.x = LERPW(wv0, gc[0].x, gc[1].x, gc[2].x, gc[3].x);
    r0.y = LERPW(wv0, gc[0].y, gc[1].y, gc[2].y, gc[3].y);
    r0.z = LERPW(wv0, gc[0].z, gc[1].z, gc[2].z, gc[3].z);
    r0.w = LERPW(wv0, gc[0].w, gc[1].w, gc[2].w, gc[3].w);
    r1.x = LERPW(wv1, gc[4].x, gc[5].x, gc[6].x, gc[7].x);
    r1.y = LERPW(wv1, gc[4].y, gc[5].y, gc[6].y, gc[7].y);
    r1.z = LERPW(wv1, gc[4].z, gc[5].z, gc[6].z, gc[7].z);
    r1.w = LERPW(wv1, gc[4].w, gc[5].w, gc[6].w, gc[7].w);
    *(uint4*)(smb + wbyte0)        = r0;
    *(uint4*)(smb + wbyte0 + 1024) = r1;

    // --- b-fragments + MFMA ---
    const s16x8 b0 = *(const s16x8*)(smb + rd0);
    const s16x8 b1 = *(const s16x8*)(smb + rd1);
#pragma unroll
    for (int mt = 0; mt < 4; ++mt) {
      const s16x8 a0 = *(const s16x8*)(wf + ((((tap * 2 + 0) * 4 + mt) * 64 + l) << 4));
      acc[mt] = __builtin_amdgcn_mfma_f32_16x16x32_bf16(a0, b0, acc[mt], 0, 0, 0);
    }
#pragma unroll
    for (int mt = 0; mt < 4; ++mt) {
      const s16x8 a1 = *(const s16x8*)(wf + ((((tap * 2 + 1) * 4 + mt) * 64 + l) << 4));
      acc[mt] = __builtin_amdgcn_mfma_f32_16x16x32_bf16(a1, b1, acc[mt], 0, 0, 0);
    }
  }
#undef GATHER
#undef LERPW

  // --- epilogue: coalesced stores (D: col=lane&15 -> pixel, row=(lane>>4)*4+j -> o) ---
#pragma unroll
  for (int mt = 0; mt < 4; ++mt)
#pragma unroll
    for (int j = 0; j < 4; ++j) {
      const int o = mt * 16 + ((l >> 4) << 2) + j;
      out[((size_t)(b * O + o) * H + h) * W + wbase + (l & 15)] = acc[mt][j];
    }
}

// ---------- fallback (round-1 kernel, used only if ws too small) ----------
namespace fb {
constexpr int WT = 32, CH = 16, NCHUNK = 4, KC = 144, WPAD = 68;
}
__global__ __launch_bounds__(THREADS, 2)
void deform_conv_fused(const float* __restrict__ x, const float* __restrict__ offs,
                       const float* __restrict__ wgt, float* __restrict__ out) {
  using namespace fb;
  __shared__ int   s_i0[KK][WT];
  __shared__ int   s_j0[KK][WT];
  __shared__ float s_fi[KK][WT];
  __shared__ float s_fj[KK][WT];
  __shared__ float s_w[KC][WPAD];
  __shared__ float s_m[KC][WT + 1];
  const int t = threadIdx.x;
  const int nwt = W / WT;
  const int wt = blockIdx.x % nwt, h = (blockIdx.x / nwt) % H, b = blockIdx.x / (nwt * H);
  const int w0 = wt * WT;
  for (int idx = t; idx < KK * WT; idx += THREADS) {
    const int k = idx / WT, p = idx % WT, w = w0 + p;
    const float oi = offs[(((size_t)b * (2 * KK) + 2 * k) * H + h) * W + w];
    const float oj = offs[(((size_t)b * (2 * KK) + 2 * k + 1) * H + h) * W + w];
    const float ci = oi + (float)(h + (k / 3) - 1), cj = oj + (float)(w + (k % 3) - 1);
    const float fli = floorf(ci), flj = floorf(cj);
    s_i0[k][p] = (int)fli; s_j0[k][p] = (int)flj;
    s_fi[k][p] = ci - fli; s_fj[k][p] = cj - flj;
  }
  float acc[8];
#pragma unroll
  for (int i = 0; i < 8; ++i) acc[i] = 0.f;
  const int p = t & (WT - 1), ob = (t >> 5) * 8;
  for (int cc = 0; cc < NCHUNK; ++cc) {
    const int c0 = cc * CH;
    __syncthreads();
    for (int idx = t; idx < O * KC; idx += THREADS)
      s_w[idx % KC][idx / KC] = wgt[(size_t)(idx / KC) * (C * KK) + (size_t)c0 * KK + idx % KC];
    for (int idx = t; idx < CH * KK * WT; idx += THREADS) {
      const int pp = idx & (WT - 1), rest = idx >> 5, k = rest % KK, cl = rest / KK;
      const int i0 = s_i0[k][pp], j0 = s_j0[k][pp], i1 = i0 + 1, j1 = j0 + 1;
      const float fi = s_fi[k][pp], fj = s_fj[k][pp];
      const float* xb = x + (size_t)(b * C + c0 + cl) * H * W;
      const float v00 = ((unsigned)i0 < (unsigned)H && (unsigned)j0 < (unsigned)W) ? xb[i0 * W + j0] : 0.f;
      const float v01 = ((unsigned)i0 < (unsigned)H && (unsigned)j1 < (unsigned)W) ? xb[i0 * W + j1] : 0.f;
      const float v10 = ((unsigned)i1 < (unsigned)H && (unsigned)j0 < (unsigned)W) ? xb[i1 * W + j0] : 0.f;
      const float v11 = ((unsigned)i1 < (unsigned)H && (unsigned)j1 < (unsigned)W) ? xb[i1 * W + j1] : 0.f;
      const float top = v00 + fj * (v01 - v00), bot = v10 + fj * (v11 - v10);
      s_m[cl * KK + k][pp] = top + fi * (bot - top);
    }
    __syncthreads();
#pragma unroll 4
    for (int k = 0; k < KC; ++k) {
      const float a = s_m[k][p];
      const float4 wv0 = *reinterpret_cast<const float4*>(&s_w[k][ob]);
      const float4 wv1 = *reinterpret_cast<const float4*>(&s_w[k][ob + 4]);
      acc[0] += a * wv0.x; acc[1] += a * wv0.y; acc[2] += a * wv0.z; acc[3] += a * wv0.w;
      acc[4] += a * wv1.x; acc[5] += a * wv1.y; acc[6] += a * wv1.z; acc[7] += a * wv1.w;
    }
  }
#pragma unroll
  for (int i = 0; i < 8; ++i)
    out[(((size_t)b * O + ob + i) * H + h) * W + w0 + p] = acc[i];
}

extern "C" void kernel_launch(void* const* d_in, const int* in_sizes, int n_in,
                              void* d_out, int out_size, void* d_ws, size_t ws_size,
                              hipStream_t stream) {
  const float* x    = (const float*)d_in[0];
  const float* offs = (const float*)d_in[1];
  const float* wgt  = (const float*)d_in[2];
  float* out = (float*)d_out;

  if (ws_size < WS_NEED) {   // fallback: round-1 kernel
    deform_conv_fused<<<B * H * (W / 32), THREADS, 0, stream>>>(x, offs, wgt, out);
    return;
  }
  char* xt = (char*)d_ws;
  unsigned short* wf = (unsigned short*)(xt + XT_BYTES);

  prep_fused<<<B * H * 2, THREADS, 0, stream>>>(x, wgt, (unsigned*)xt, wf);
  deform_mfma<<<B * H * 2, THREADS, 0, stream>>>(offs, xt, (const char*)wf, out);
}

// Round 5
// 36.987 us; speedup vs baseline: 1.5159x; 1.0090x over previous
//
#include <hip/hip_runtime.h>

namespace {
constexpr int B = 4, C = 64, H = 128, W = 128, O = 64, KK = 9;
constexpr int THREADS = 256;
constexpr int WF_ELEMS = KK * 2 * 4 * 64 * 8;                   // 36864
constexpr size_t XT_BYTES = (size_t)B * H * W * C * 2;          // 16,777,216
constexpr size_t WF_BYTES = (size_t)WF_ELEMS * 2;               // 73,728
constexpr size_t WS_NEED  = XT_BYTES + WF_BYTES;
}

typedef float  f32x4 __attribute__((ext_vector_type(4)));
typedef short  s16x8 __attribute__((ext_vector_type(8)));

__device__ __forceinline__ float lo16(unsigned u) { return __uint_as_float(u << 16); }
__device__ __forceinline__ float hi16(unsigned u) { return __uint_as_float(u & 0xFFFF0000u); }
__device__ __forceinline__ unsigned bpack(float a, float b) {   // RNE bf16 pair
  unsigned ua = __float_as_uint(a); ua += 0x7FFFu + ((ua >> 16) & 1u);
  unsigned ub = __float_as_uint(b); ub += 0x7FFFu + ((ub >> 16) & 1u);
  return (ua >> 16) | (ub & 0xFFFF0000u);
}

// ---------- prep: x[b][c][h][w] f32 -> x_t[b][h][w][c] bf16,  + weight->frag ----------
__global__ __launch_bounds__(THREADS)
void prep_fused(const float* __restrict__ x, const float* __restrict__ wgt,
                unsigned* __restrict__ xt_u32, unsigned short* __restrict__ wf) {
  __shared__ float st[64][65];
  const int t = threadIdx.x;

  // weight -> bf16 A-fragment order (first 144 blocks, one elem/thread)
  // o = mt*16 + (lane&15), c = ks*32 + (lane>>4)*8 + e
  const int gid = blockIdx.x * THREADS + t;
  if (gid < WF_ELEMS) {
    const int e = gid & 7, lane = (gid >> 3) & 63, mt = (gid >> 9) & 3;
    const int ks = (gid >> 11) & 1, tap = gid >> 12;
    const int o = mt * 16 + (lane & 15);
    const int c = ks * 32 + ((lane >> 4) << 3) + e;
    unsigned u = __float_as_uint(wgt[(size_t)o * (C * KK) + c * KK + tap]);
    u += 0x7FFFu + ((u >> 16) & 1u);
    wf[gid] = (unsigned short)(u >> 16);
  }

  const int half = blockIdx.x & 1, h = (blockIdx.x >> 1) & 127, b = blockIdx.x >> 8;
  const int w0 = half * 64;
#pragma unroll
  for (int it = 0; it < 16; ++it) {
    const int w = t & 63, c = it * 4 + (t >> 6);
    st[w][c] = x[((size_t)(b * C + c) * H + h) * W + w0 + w];
  }
  __syncthreads();
#pragma unroll
  for (int it = 0; it < 8; ++it) {
    const int idx = it * THREADS + t;
    const int w = idx >> 5, c2 = (idx & 31) * 2;
    xt_u32[(size_t)(((b * H + h) * W) + w0 + w) * 32 + (c2 >> 1)] = bpack(st[w][c2], st[w][c2 + 1]);
  }
}

// ---------- main: fused deform-sample + LDS-staged MFMA, 4-stage half-tap pipeline ----------
__global__ __launch_bounds__(THREADS) __attribute__((amdgpu_waves_per_eu(4, 4)))
void deform_mfma(const float* __restrict__ offs, const char* __restrict__ xt,
                 const char* __restrict__ wf, float* __restrict__ out) {
  __shared__ float          s_p[4][KK][16][8];   // sampling params (18.4 KB)
  __shared__ unsigned short s_m[64 * 64];        // [block pix][c] bf16, swizzled (8 KB)

  const int t = threadIdx.x, l = t & 63, wid = t >> 6;
  const int half = blockIdx.x & 1, h = (blockIdx.x >> 1) & 127, b = blockIdx.x >> 8;
  const int wbase = half * 64 + wid * 16;        // wave's first pixel (global w)

  // --- sampling params: this wave's 16 pixels x 9 taps (wave-private, no barrier) ---
#pragma unroll
  for (int it = 0; it < 3; ++it) {
    const int item = it * 64 + l;
    if (item < KK * 16) {
      const int tap = item >> 4, pix = item & 15;
      const int ki = tap / 3, kj = tap - ki * 3;
      const int w = wbase + pix;
      const float* ob = offs + ((size_t)b * (2 * KK) + 2 * tap) * (H * W) + h * W + w;
      const float oi = ob[0], oj = ob[H * W];
      const float ci = oi + (float)(h + ki - 1);
      const float cj = oj + (float)(w + kj - 1);
      const float fli = floorf(ci), flj = floorf(cj);
      const int i0 = (int)fli, j0 = (int)flj, i1 = i0 + 1, j1 = j0 + 1;
      const float fi = ci - fli, fj = cj - flj, gi = 1.f - fi, gj = 1.f - fj;
      const bool bi0 = (unsigned)i0 < (unsigned)H, bi1 = (unsigned)i1 < (unsigned)H;
      const bool bj0 = (unsigned)j0 < (unsigned)W, bj1 = (unsigned)j1 < (unsigned)W;
      const int ic0 = min(max(i0, 0), H - 1), ic1 = min(max(i1, 0), H - 1);
      const int jc0 = min(max(j0, 0), W - 1), jc1 = min(max(j1, 0), W - 1);
      float* sp = &s_p[wid][tap][pix][0];
      sp[0] = gi * gj * (float)(bi0 && bj0);
      sp[1] = gi * fj * (float)(bi0 && bj1);
      sp[2] = fi * gj * (float)(bi1 && bj0);
      sp[3] = fi * fj * (float)(bi1 && bj1);
      sp[4] = __int_as_float(((b * H + ic0) * W + jc0) << 7);   // byte addr in x_t
      sp[5] = __int_as_float(((b * H + ic0) * W + jc1) << 7);
      sp[6] = __int_as_float(((b * H + ic1) * W + jc0) << 7);
      sp[7] = __int_as_float(((b * H + ic1) * W + jc1) << 7);
    }
  }

  // gather lane map: 8 lanes (oct 0..7) cover one pixel-corner's 128B contiguously
  const int pix8 = l >> 3;          // pixel within 8-px stage group
  const int oct  = l & 7;
  const int cb   = oct << 4;

  char* smb = (char*)s_m;
  // LDS write (swizzled): stage hs row = wid*16 + hs*8 + pix8, slot = oct ^ pix8
  const int wb = ((wid * 16 + pix8) << 7) + ((oct ^ pix8) << 4);   // hs=1 -> +1024
  // b-frag reads: row rr, slot (ks*4 + (l>>4)) ^ (rr&7)
  const int rr  = wid * 16 + (l & 15);
  const int rd0 = (rr << 7) + ((((l >> 4)    ) ^ (l & 7)) << 4);
  const int rd1 = (rr << 7) + (((4 + (l >> 4)) ^ (l & 7)) << 4);

  f32x4 acc[4];
#pragma unroll
  for (int mt = 0; mt < 4; ++mt) acc[mt] = (f32x4)0.f;

  // stage S = (tap, half): 8 pixels x 4 corners, 16 VGPR. Ring of 4 -> 2-tap cover.
  uint4 g[4][4];
#define ISSUE(S) do {                                                          \
    const int tap_ = (S) >> 1, hs_ = (S) & 1;                                  \
    const float4 af_ = *(const float4*)&s_p[wid][tap_][hs_ * 8 + pix8][4];     \
    g[(S) & 3][0] = *(const uint4*)(xt + __float_as_int(af_.x) + cb);          \
    g[(S) & 3][1] = *(const uint4*)(xt + __float_as_int(af_.y) + cb);          \
    g[(S) & 3][2] = *(const uint4*)(xt + __float_as_int(af_.z) + cb);          \
    g[(S) & 3][3] = *(const uint4*)(xt + __float_as_int(af_.w) + cb);          \
  } while (0)

#define LERPW(wv, c0_, c1_, c2_, c3_) bpack(                                   \
    wv.x * lo16(c0_) + wv.y * lo16(c1_) + wv.z * lo16(c2_) + wv.w * lo16(c3_), \
    wv.x * hi16(c0_) + wv.y * hi16(c1_) + wv.z * hi16(c2_) + wv.w * hi16(c3_))

  ISSUE(0); ISSUE(1); ISSUE(2); ISSUE(3);

#pragma unroll
  for (int s = 0; s < 18; ++s) {
    const int tap = s >> 1, hs = s & 1;

    // --- lerp stage s (consumes ring slot s&3), write swizzled LDS ---
    const float4 wv = *(const float4*)&s_p[wid][tap][hs * 8 + pix8][0];
    uint4* gc = g[s & 3];
    uint4 r;
    r.x = LERPW(wv, gc[0].x, gc[1].x, gc[2].x, gc[3].x);
    r.y = LERPW(wv, gc[0].y, gc[1].y, gc[2].y, gc[3].y);
    r.z = LERPW(wv, gc[0].z, gc[1].z, gc[2].z, gc[3].z);
    r.w = LERPW(wv, gc[0].w, gc[1].w, gc[2].w, gc[3].w);
    *(uint4*)(smb + wb + hs * 1024) = r;

    // --- refill the slot just freed (4 stages ahead) ---
    if (s + 4 < 18) ISSUE(s + 4);

    // --- tap complete: b-fragments + 8 MFMA ---
    if (hs == 1) {
      const s16x8 b0 = *(const s16x8*)(smb + rd0);
      const s16x8 b1 = *(const s16x8*)(smb + rd1);
#pragma unroll
      for (int mt = 0; mt < 4; ++mt) {
        const s16x8 a0 = *(const s16x8*)(wf + ((((tap * 2 + 0) * 4 + mt) * 64 + l) << 4));
        acc[mt] = __builtin_amdgcn_mfma_f32_16x16x32_bf16(a0, b0, acc[mt], 0, 0, 0);
      }
#pragma unroll
      for (int mt = 0; mt < 4; ++mt) {
        const s16x8 a1 = *(const s16x8*)(wf + ((((tap * 2 + 1) * 4 + mt) * 64 + l) << 4));
        acc[mt] = __builtin_amdgcn_mfma_f32_16x16x32_bf16(a1, b1, acc[mt], 0, 0, 0);
      }
    }
  }
#undef ISSUE
#undef LERPW

  // --- epilogue: coalesced stores (D: col=lane&15 -> pixel, row=(lane>>4)*4+j -> o) ---
#pragma unroll
  for (int mt = 0; mt < 4; ++mt)
#pragma unroll
    for (int j = 0; j < 4; ++j) {
      const int o = mt * 16 + ((l >> 4) << 2) + j;
      out[((size_t)(b * O + o) * H + h) * W + wbase + (l & 15)] = acc[mt][j];
    }
}

// ---------- fallback (round-1 kernel, used only if ws too small) ----------
namespace fb {
constexpr int WT = 32, CH = 16, NCHUNK = 4, KC = 144, WPAD = 68;
}
__global__ __launch_bounds__(THREADS, 2)
void deform_conv_fused(const float* __restrict__ x, const float* __restrict__ offs,
                       const float* __restrict__ wgt, float* __restrict__ out) {
  using namespace fb;
  __shared__ int   s_i0[KK][WT];
  __shared__ int   s_j0[KK][WT];
  __shared__ float s_fi[KK][WT];
  __shared__ float s_fj[KK][WT];
  __shared__ float s_w[KC][WPAD];
  __shared__ float s_m[KC][WT + 1];
  const int t = threadIdx.x;
  const int nwt = W / WT;
  const int wt = blockIdx.x % nwt, h = (blockIdx.x / nwt) % H, b = blockIdx.x / (nwt * H);
  const int w0 = wt * WT;
  for (int idx = t; idx < KK * WT; idx += THREADS) {
    const int k = idx / WT, p = idx % WT, w = w0 + p;
    const float oi = offs[(((size_t)b * (2 * KK) + 2 * k) * H + h) * W + w];
    const float oj = offs[(((size_t)b * (2 * KK) + 2 * k + 1) * H + h) * W + w];
    const float ci = oi + (float)(h + (k / 3) - 1), cj = oj + (float)(w + (k % 3) - 1);
    const float fli = floorf(ci), flj = floorf(cj);
    s_i0[k][p] = (int)fli; s_j0[k][p] = (int)flj;
    s_fi[k][p] = ci - fli; s_fj[k][p] = cj - flj;
  }
  float acc[8];
#pragma unroll
  for (int i = 0; i < 8; ++i) acc[i] = 0.f;
  const int p = t & (WT - 1), ob = (t >> 5) * 8;
  for (int cc = 0; cc < NCHUNK; ++cc) {
    const int c0 = cc * CH;
    __syncthreads();
    for (int idx = t; idx < O * KC; idx += THREADS)
      s_w[idx % KC][idx / KC] = wgt[(size_t)(idx / KC) * (C * KK) + (size_t)c0 * KK + idx % KC];
    for (int idx = t; idx < CH * KK * WT; idx += THREADS) {
      const int pp = idx & (WT - 1), rest = idx >> 5, k = rest % KK, cl = rest / KK;
      const int i0 = s_i0[k][pp], j0 = s_j0[k][pp], i1 = i0 + 1, j1 = j0 + 1;
      const float fi = s_fi[k][pp], fj = s_fj[k][pp];
      const float* xb = x + (size_t)(b * C + c0 + cl) * H * W;
      const float v00 = ((unsigned)i0 < (unsigned)H && (unsigned)j0 < (unsigned)W) ? xb[i0 * W + j0] : 0.f;
      const float v01 = ((unsigned)i0 < (unsigned)H && (unsigned)j1 < (unsigned)W) ? xb[i0 * W + j1] : 0.f;
      const float v10 = ((unsigned)i1 < (unsigned)H && (unsigned)j0 < (unsigned)W) ? xb[i1 * W + j0] : 0.f;
      const float v11 = ((unsigned)i1 < (unsigned)H && (unsigned)j1 < (unsigned)W) ? xb[i1 * W + j1] : 0.f;
      const float top = v00 + fj * (v01 - v00), bot = v10 + fj * (v11 - v10);
      s_m[cl * KK + k][pp] = top + fi * (bot - top);
    }
    __syncthreads();
#pragma unroll 4
    for (int k = 0; k < KC; ++k) {
      const float a = s_m[k][p];
      const float4 wv0 = *reinterpret_cast<const float4*>(&s_w[k][ob]);
      const float4 wv1 = *reinterpret_cast<const float4*>(&s_w[k][ob + 4]);
      acc[0] += a * wv0.x; acc[1] += a * wv0.y; acc[2] += a * wv0.z; acc[3] += a * wv0.w;
      acc[4] += a * wv1.x; acc[5] += a * wv1.y; acc[6] += a * wv1.z; acc[7] += a * wv1.w;
    }
  }
#pragma unroll
  for (int i = 0; i < 8; ++i)
    out[(((size_t)b * O + ob + i) * H + h) * W + w0 + p] = acc[i];
}

extern "C" void kernel_launch(void* const* d_in, const int* in_sizes, int n_in,
                              void* d_out, int out_size, void* d_ws, size_t ws_size,
                              hipStream_t stream) {
  const float* x    = (const float*)d_in[0];
  const float* offs = (const float*)d_in[1];
  const float* wgt  = (const float*)d_in[2];
  float* out = (float*)d_out;

  if (ws_size < WS_NEED) {   // fallback: round-1 kernel
    deform_conv_fused<<<B * H * (W / 32), THREADS, 0, stream>>>(x, offs, wgt, out);
    return;
  }
  char* xt = (char*)d_ws;
  unsigned short* wf = (unsigned short*)(xt + XT_BYTES);

  prep_fused<<<B * H * 2, THREADS, 0, stream>>>(x, wgt, (unsigned*)xt, wf);
  deform_mfma<<<B * H * 2, THREADS, 0, stream>>>(offs, xt, (const char*)wf, out);
}

// Round 6
// 35.726 us; speedup vs baseline: 1.5695x; 1.0353x over previous
//
#include <hip/hip_runtime.h>

namespace {
constexpr int B = 4, C = 64, H = 128, W = 128, O = 64, KK = 9;
constexpr int PREPT = 256;
constexpr int WF_ELEMS = KK * 2 * 4 * 64 * 8;                   // 36864
constexpr size_t XT_BYTES = (size_t)B * H * W * C * 2;          // 16,777,216
constexpr size_t WF_BYTES = (size_t)WF_ELEMS * 2;               // 73,728
constexpr size_t WS_NEED  = XT_BYTES + WF_BYTES;
}

typedef float  f32x4 __attribute__((ext_vector_type(4)));
typedef short  s16x8 __attribute__((ext_vector_type(8)));

__device__ __forceinline__ float lo16(unsigned u) { return __uint_as_float(u << 16); }
__device__ __forceinline__ float hi16(unsigned u) { return __uint_as_float(u & 0xFFFF0000u); }
__device__ __forceinline__ unsigned bpack(float a, float b) {   // RNE bf16 pair
  unsigned ua = __float_as_uint(a); ua += 0x7FFFu + ((ua >> 16) & 1u);
  unsigned ub = __float_as_uint(b); ub += 0x7FFFu + ((ub >> 16) & 1u);
  return (ua >> 16) | (ub & 0xFFFF0000u);
}

// ---------- prep: x[b][c][h][w] f32 -> x_t[b][h][w][c] bf16,  + weight->frag ----------
__global__ __launch_bounds__(PREPT)
void prep_fused(const float* __restrict__ x, const float* __restrict__ wgt,
                unsigned* __restrict__ xt_u32, unsigned short* __restrict__ wf) {
  __shared__ float st[64][65];
  const int t = threadIdx.x;

  // weight -> bf16 A-fragment order: o = mt*16 + (lane&15), c = ks*32 + (lane>>4)*8 + e
  const int gid = blockIdx.x * PREPT + t;
  if (gid < WF_ELEMS) {
    const int e = gid & 7, lane = (gid >> 3) & 63, mt = (gid >> 9) & 3;
    const int ks = (gid >> 11) & 1, tap = gid >> 12;
    const int o = mt * 16 + (lane & 15);
    const int c = ks * 32 + ((lane >> 4) << 3) + e;
    unsigned u = __float_as_uint(wgt[(size_t)o * (C * KK) + c * KK + tap]);
    u += 0x7FFFu + ((u >> 16) & 1u);
    wf[gid] = (unsigned short)(u >> 16);
  }

  const int half = blockIdx.x & 1, h = (blockIdx.x >> 1) & 127, b = blockIdx.x >> 8;
  const int w0 = half * 64;
#pragma unroll
  for (int it = 0; it < 16; ++it) {
    const int w = t & 63, c = it * 4 + (t >> 6);
    st[w][c] = x[((size_t)(b * C + c) * H + h) * W + w0 + w];
  }
  __syncthreads();
#pragma unroll
  for (int it = 0; it < 8; ++it) {
    const int idx = it * PREPT + t;
    const int w = idx >> 5, c2 = (idx & 31) * 2;
    xt_u32[(size_t)(((b * H + h) * W) + w0 + w) * 32 + (c2 >> 1)] = bpack(st[w][c2], st[w][c2 + 1]);
  }
}

// ---------- main: 32 px/wave, 2-wave blocks, ring-4 pipeline, XCD-swizzled ----------
__global__ __launch_bounds__(128) __attribute__((amdgpu_waves_per_eu(3, 3)))
void deform_mfma(const float* __restrict__ offs, const char* __restrict__ xt,
                 const char* __restrict__ wf, float* __restrict__ out) {
  __shared__ float          s_p[2][KK][32][8];   // sampling params (18.4 KB)
  __shared__ unsigned short s_m[64 * 64];        // [block px][c] bf16, swizzled (8 KB)

  const int t = threadIdx.x, l = t & 63, wid = t >> 6;
  // bijective XCD swizzle: 1024 blocks -> each XCD gets 64 consecutive rows of one image
  const int nid  = (blockIdx.x & 7) * 128 + (blockIdx.x >> 3);
  const int half = nid & 1, h = (nid >> 1) & 127, b = nid >> 8;
  const int wbase = half * 64 + wid * 32;        // wave's first pixel (global w)

  // --- sampling params: this wave's 32 pixels x 9 taps (wave-private, no barrier) ---
#pragma unroll
  for (int it = 0; it < 5; ++it) {
    const int item = it * 64 + l;
    if (item < KK * 32) {
      const int tap = item >> 5, pix = item & 31;
      const int ki = tap / 3, kj = tap - ki * 3;
      const int w = wbase + pix;
      const float* ob = offs + ((size_t)b * (2 * KK) + 2 * tap) * (H * W) + h * W + w;
      const float oi = ob[0], oj = ob[H * W];
      const float ci = oi + (float)(h + ki - 1);
      const float cj = oj + (float)(w + kj - 1);
      const float fli = floorf(ci), flj = floorf(cj);
      const int i0 = (int)fli, j0 = (int)flj, i1 = i0 + 1, j1 = j0 + 1;
      const float fi = ci - fli, fj = cj - flj, gi = 1.f - fi, gj = 1.f - fj;
      const bool bi0 = (unsigned)i0 < (unsigned)H, bi1 = (unsigned)i1 < (unsigned)H;
      const bool bj0 = (unsigned)j0 < (unsigned)W, bj1 = (unsigned)j1 < (unsigned)W;
      const int ic0 = min(max(i0, 0), H - 1), ic1 = min(max(i1, 0), H - 1);
      const int jc0 = min(max(j0, 0), W - 1), jc1 = min(max(j1, 0), W - 1);
      float* sp = &s_p[wid][tap][pix][0];
      sp[0] = gi * gj * (float)(bi0 && bj0);
      sp[1] = gi * fj * (float)(bi0 && bj1);
      sp[2] = fi * gj * (float)(bi1 && bj0);
      sp[3] = fi * fj * (float)(bi1 && bj1);
      sp[4] = __int_as_float(((b * H + ic0) * W + jc0) << 7);   // byte addr in x_t
      sp[5] = __int_as_float(((b * H + ic0) * W + jc1) << 7);
      sp[6] = __int_as_float(((b * H + ic1) * W + jc0) << 7);
      sp[7] = __int_as_float(((b * H + ic1) * W + jc1) << 7);
    }
  }

  // gather lane map: 8 lanes (oct 0..7) cover one pixel-corner's 128B contiguously
  const int pix8 = l >> 3;          // pixel within 8-px stage group
  const int oct  = l & 7;
  const int cb   = oct << 4;

  char* smb = (char*)s_m;
  // LDS write (swizzled): stage q row = wid*32 + q*8 + pix8, slot = oct ^ pix8
  const int wb0 = ((wid * 32 + pix8) << 7) + ((oct ^ pix8) << 4);  // + q*1024
  // b-frag reads: row rr = wid*32 + nt*16 + (l&15); chunk (ks*4 + l>>4) ^ (rr&7)
  const int rdb = (wid * 32 + (l & 15)) << 7;                      // + nt*2048
  const int sl0 = (((l >> 4)    ) ^ (l & 7)) << 4;                 // ks=0
  const int sl1 = (((l >> 4) + 4) ^ (l & 7)) << 4;                 // ks=1

  f32x4 acc[2][4];
#pragma unroll
  for (int nt = 0; nt < 2; ++nt)
#pragma unroll
    for (int mt = 0; mt < 4; ++mt) acc[nt][mt] = (f32x4)0.f;

  uint4 g[4][4];   // ring: slot q <-> stage q of current prefetch tap
#define ISSUE(TAPX, Q) do {                                                    \
    const float4 af_ = *(const float4*)&s_p[wid][(TAPX)][(Q) * 8 + pix8][4];   \
    g[Q][0] = *(const uint4*)(xt + __float_as_int(af_.x) + cb);                \
    g[Q][1] = *(const uint4*)(xt + __float_as_int(af_.y) + cb);                \
    g[Q][2] = *(const uint4*)(xt + __float_as_int(af_.z) + cb);                \
    g[Q][3] = *(const uint4*)(xt + __float_as_int(af_.w) + cb);                \
  } while (0)

#define LERPW(wv, c0_, c1_, c2_, c3_) bpack(                                   \
    wv.x * lo16(c0_) + wv.y * lo16(c1_) + wv.z * lo16(c2_) + wv.w * lo16(c3_), \
    wv.x * hi16(c0_) + wv.y * hi16(c1_) + wv.z * hi16(c2_) + wv.w * hi16(c3_))

#define STAGE(TAPV, Q) do {                                                    \
    const float4 wv = *(const float4*)&s_p[wid][(TAPV)][(Q) * 8 + pix8][0];    \
    uint4* gc = g[Q];                                                          \
    uint4 r;                                                                   \
    r.x = LERPW(wv, gc[0].x, gc[1].x, gc[2].x, gc[3].x);                       \
    r.y = LERPW(wv, gc[0].y, gc[1].y, gc[2].y, gc[3].y);                       \
    r.z = LERPW(wv, gc[0].z, gc[1].z, gc[2].z, gc[3].z);                       \
    r.w = LERPW(wv, gc[0].w, gc[1].w, gc[2].w, gc[3].w);                       \
    *(uint4*)(smb + wb0 + (Q) * 1024) = r;                                     \
  } while (0)

#define MFMA_TAP(TAPV) do {                                                    \
    const s16x8 b00 = *(const s16x8*)(smb + rdb + sl0);                        \
    const s16x8 b01 = *(const s16x8*)(smb + rdb + sl1);                        \
    const s16x8 b10 = *(const s16x8*)(smb + rdb + 2048 + sl0);                 \
    const s16x8 b11 = *(const s16x8*)(smb + rdb + 2048 + sl1);                 \
    _Pragma("unroll")                                                          \
    for (int mt = 0; mt < 4; ++mt) {                                           \
      const s16x8 a0 = *(const s16x8*)(wf + (((((TAPV)*2+0)*4+mt)*64 + l) << 4)); \
      acc[0][mt] = __builtin_amdgcn_mfma_f32_16x16x32_bf16(a0, b00, acc[0][mt], 0, 0, 0); \
      acc[1][mt] = __builtin_amdgcn_mfma_f32_16x16x32_bf16(a0, b10, acc[1][mt], 0, 0, 0); \
      const s16x8 a1 = *(const s16x8*)(wf + (((((TAPV)*2+1)*4+mt)*64 + l) << 4)); \
      acc[0][mt] = __builtin_amdgcn_mfma_f32_16x16x32_bf16(a1, b01, acc[0][mt], 0, 0, 0); \
      acc[1][mt] = __builtin_amdgcn_mfma_f32_16x16x32_bf16(a1, b11, acc[1][mt], 0, 0, 0); \
    }                                                                          \
  } while (0)

#pragma unroll
  for (int q = 0; q < 4; ++q) ISSUE(0, q);

#pragma unroll 1
  for (int tap = 0; tap < KK - 1; ++tap) {
#pragma unroll
    for (int q = 0; q < 4; ++q) {
      STAGE(tap, q);
      ISSUE(tap + 1, q);                       // refill freed ring slot
      __builtin_amdgcn_sched_barrier(0);       // pin: no sinking of prefetches
    }
    MFMA_TAP(tap);
  }
  // tail: tap = KK-1, no prefetch
#pragma unroll
  for (int q = 0; q < 4; ++q) STAGE(KK - 1, q);
  MFMA_TAP(KK - 1);

#undef ISSUE
#undef LERPW
#undef STAGE
#undef MFMA_TAP

  // --- epilogue: coalesced stores (D: col=lane&15 -> pixel, row=(lane>>4)*4+j -> o) ---
#pragma unroll
  for (int nt = 0; nt < 2; ++nt)
#pragma unroll
    for (int mt = 0; mt < 4; ++mt)
#pragma unroll
      for (int j = 0; j < 4; ++j) {
        const int o = mt * 16 + ((l >> 4) << 2) + j;
        out[((size_t)(b * O + o) * H + h) * W + wbase + nt * 16 + (l & 15)] = acc[nt][mt][j];
      }
}

// ---------- fallback (round-1 kernel, used only if ws too small) ----------
namespace fb {
constexpr int WT = 32, CH = 16, NCHUNK = 4, KC = 144, WPAD = 68;
}
__global__ __launch_bounds__(PREPT, 2)
void deform_conv_fused(const float* __restrict__ x, const float* __restrict__ offs,
                       const float* __restrict__ wgt, float* __restrict__ out) {
  using namespace fb;
  __shared__ int   s_i0[KK][WT];
  __shared__ int   s_j0[KK][WT];
  __shared__ float s_fi[KK][WT];
  __shared__ float s_fj[KK][WT];
  __shared__ float s_w[KC][WPAD];
  __shared__ float s_m[KC][WT + 1];
  const int t = threadIdx.x;
  const int nwt = W / WT;
  const int wt = blockIdx.x % nwt, h = (blockIdx.x / nwt) % H, b = blockIdx.x / (nwt * H);
  const int w0 = wt * WT;
  for (int idx = t; idx < KK * WT; idx += PREPT) {
    const int k = idx / WT, p = idx % WT, w = w0 + p;
    const float oi = offs[(((size_t)b * (2 * KK) + 2 * k) * H + h) * W + w];
    const float oj = offs[(((size_t)b * (2 * KK) + 2 * k + 1) * H + h) * W + w];
    const float ci = oi + (float)(h + (k / 3) - 1), cj = oj + (float)(w + (k % 3) - 1);
    const float fli = floorf(ci), flj = floorf(cj);
    s_i0[k][p] = (int)fli; s_j0[k][p] = (int)flj;
    s_fi[k][p] = ci - fli; s_fj[k][p] = cj - flj;
  }
  float acc[8];
#pragma unroll
  for (int i = 0; i < 8; ++i) acc[i] = 0.f;
  const int p = t & (WT - 1), ob = (t >> 5) * 8;
  for (int cc = 0; cc < NCHUNK; ++cc) {
    const int c0 = cc * CH;
    __syncthreads();
    for (int idx = t; idx < O * KC; idx += PREPT)
      s_w[idx % KC][idx / KC] = wgt[(size_t)(idx / KC) * (C * KK) + (size_t)c0 * KK + idx % KC];
    for (int idx = t; idx < CH * KK * WT; idx += PREPT) {
      const int pp = idx & (WT - 1), rest = idx >> 5, k = rest % KK, cl = rest / KK;
      const int i0 = s_i0[k][pp], j0 = s_j0[k][pp], i1 = i0 + 1, j1 = j0 + 1;
      const float fi = s_fi[k][pp], fj = s_fj[k][pp];
      const float* xb = x + (size_t)(b * C + c0 + cl) * H * W;
      const float v00 = ((unsigned)i0 < (unsigned)H && (unsigned)j0 < (unsigned)W) ? xb[i0 * W + j0] : 0.f;
      const float v01 = ((unsigned)i0 < (unsigned)H && (unsigned)j1 < (unsigned)W) ? xb[i0 * W + j1] : 0.f;
      const float v10 = ((unsigned)i1 < (unsigned)H && (unsigned)j0 < (unsigned)W) ? xb[i1 * W + j0] : 0.f;
      const float v11 = ((unsigned)i1 < (unsigned)H && (unsigned)j1 < (unsigned)W) ? xb[i1 * W + j1] : 0.f;
      const float top = v00 + fj * (v01 - v00), bot = v10 + fj * (v11 - v10);
      s_m[cl * KK + k][pp] = top + fi * (bot - top);
    }
    __syncthreads();
#pragma unroll 4
    for (int k = 0; k < KC; ++k) {
      const float a = s_m[k][p];
      const float4 wv0 = *reinterpret_cast<const float4*>(&s_w[k][ob]);
      const float4 wv1 = *reinterpret_cast<const float4*>(&s_w[k][ob + 4]);
      acc[0] += a * wv0.x; acc[1] += a * wv0.y; acc[2] += a * wv0.z; acc[3] += a * wv0.w;
      acc[4] += a * wv1.x; acc[5] += a * wv1.y; acc[6] += a * wv1.z; acc[7] += a * wv1.w;
    }
  }
#pragma unroll
  for (int i = 0; i < 8; ++i)
    out[(((size_t)b * O + ob + i) * H + h) * W + w0 + p] = acc[i];
}

extern "C" void kernel_launch(void* const* d_in, const int* in_sizes, int n_in,
                              void* d_out, int out_size, void* d_ws, size_t ws_size,
                              hipStream_t stream) {
  const float* x    = (const float*)d_in[0];
  const float* offs = (const float*)d_in[1];
  const float* wgt  = (const float*)d_in[2];
  float* out = (float*)d_out;

  if (ws_size < WS_NEED) {   // fallback: round-1 kernel
    deform_conv_fused<<<B * H * (W / 32), PREPT, 0, stream>>>(x, offs, wgt, out);
    return;
  }
  char* xt = (char*)d_ws;
  unsigned short* wf = (unsigned short*)(xt + XT_BYTES);

  prep_fused<<<B * H * 2, PREPT, 0, stream>>>(x, wgt, (unsigned*)xt, wf);
  deform_mfma<<<B * H * 2, 128, 0, stream>>>(offs, xt, (const char*)wf, out);
}

// Round 7
// 34.976 us; speedup vs baseline: 1.6031x; 1.0214x over previous
//
#include <hip/hip_runtime.h>

namespace {
constexpr int B = 4, C = 64, H = 128, W = 128, O = 64, KK = 9;
constexpr int PREPT = 256;
constexpr int WF_ELEMS = KK * 2 * 4 * 64 * 8;                   // 36864
constexpr size_t XT_BYTES = (size_t)B * H * W * C * 2;          // 16,777,216
constexpr size_t WF_BYTES = (size_t)WF_ELEMS * 2;               // 73,728 (8KB per tap)
constexpr size_t WS_NEED  = XT_BYTES + WF_BYTES;
}

typedef float  f32x4 __attribute__((ext_vector_type(4)));
typedef short  s16x8 __attribute__((ext_vector_type(8)));

__device__ __forceinline__ float lo16(unsigned u) { return __uint_as_float(u << 16); }
__device__ __forceinline__ float hi16(unsigned u) { return __uint_as_float(u & 0xFFFF0000u); }
__device__ __forceinline__ unsigned bpack(float a, float b) {   // RNE bf16 pair
  unsigned ua = __float_as_uint(a); ua += 0x7FFFu + ((ua >> 16) & 1u);
  unsigned ub = __float_as_uint(b); ub += 0x7FFFu + ((ub >> 16) & 1u);
  return (ua >> 16) | (ub & 0xFFFF0000u);
}
__device__ __forceinline__ void gload16(const void* g, void* l) {
  __builtin_amdgcn_global_load_lds(
      (const __attribute__((address_space(1))) unsigned*)g,
      (__attribute__((address_space(3))) unsigned*)l, 16, 0, 0);
}

// ---------- prep: x[b][c][h][w] f32 -> x_t[b][h][w][c] bf16,  + weight->frag ----------
__global__ __launch_bounds__(PREPT)
void prep_fused(const float* __restrict__ x, const float* __restrict__ wgt,
                unsigned* __restrict__ xt_u32, unsigned short* __restrict__ wf) {
  __shared__ float st[64][65];
  const int t = threadIdx.x;

  // weight -> bf16 A-fragment order: [tap][ks][mt][lane][e]
  // o = mt*16 + (lane&15), c = ks*32 + (lane>>4)*8 + e
  const int gid = blockIdx.x * PREPT + t;
  if (gid < WF_ELEMS) {
    const int e = gid & 7, lane = (gid >> 3) & 63, mt = (gid >> 9) & 3;
    const int ks = (gid >> 11) & 1, tap = gid >> 12;
    const int o = mt * 16 + (lane & 15);
    const int c = ks * 32 + ((lane >> 4) << 3) + e;
    unsigned u = __float_as_uint(wgt[(size_t)o * (C * KK) + c * KK + tap]);
    u += 0x7FFFu + ((u >> 16) & 1u);
    wf[gid] = (unsigned short)(u >> 16);
  }

  const int half = blockIdx.x & 1, h = (blockIdx.x >> 1) & 127, b = blockIdx.x >> 8;
  const int w0 = half * 64;
#pragma unroll
  for (int it = 0; it < 16; ++it) {
    const int w = t & 63, c = it * 4 + (t >> 6);
    st[w][c] = x[((size_t)(b * C + c) * H + h) * W + w0 + w];
  }
  __syncthreads();
#pragma unroll
  for (int it = 0; it < 8; ++it) {
    const int idx = it * PREPT + t;
    const int w = idx >> 5, c2 = (idx & 31) * 2;
    xt_u32[(size_t)(((b * H + h) * W) + w0 + w) * 32 + (c2 >> 1)] = bpack(st[w][c2], st[w][c2 + 1]);
  }
}

// ---------- main: 16 px/wave, 4 waves/block, wf staged via global_load_lds ----------
__global__ __launch_bounds__(256) __attribute__((amdgpu_waves_per_eu(4, 4)))
void deform_mfma(const float* __restrict__ offs, const char* __restrict__ xt,
                 const char* __restrict__ wfg, float* __restrict__ out) {
  __shared__ unsigned short s_wf[2][4096];     // 16 KB: dbuf of one tap's A-fragments
  __shared__ unsigned short s_m[64 * 64];      // 8 KB:  [block px][c] bf16, swizzled
  __shared__ unsigned s_pw[4][KK][16][2];      // 4.5 KB: bf16x4 bilinear weights
  __shared__ unsigned s_pa[4][KK][16][4];      // 9 KB:  4 corner byte-addrs

  const int t = threadIdx.x, l = t & 63, wid = t >> 6;
  // bijective XCD swizzle: each XCD gets 64 consecutive rows of one image
  const int nid  = (blockIdx.x & 7) * 128 + (blockIdx.x >> 3);
  const int half = nid & 1, h = (nid >> 1) & 127, b = nid >> 8;
  const int wbase = half * 64 + wid * 16;      // wave's first pixel (global w)

  // --- sampling params: wave's 16 px x 9 taps (wave-private; compact 24B/entry) ---
#pragma unroll
  for (int it = 0; it < 3; ++it) {
    const int item = it * 64 + l;
    if (item < KK * 16) {
      const int tap = item >> 4, pix = item & 15;
      const int ki = tap / 3, kj = tap - ki * 3;
      const int w = wbase + pix;
      const float* ob = offs + ((size_t)b * (2 * KK) + 2 * tap) * (H * W) + h * W + w;
      const float oi = ob[0], oj = ob[H * W];
      const float ci = oi + (float)(h + ki - 1);
      const float cj = oj + (float)(w + kj - 1);
      const float fli = floorf(ci), flj = floorf(cj);
      const int i0 = (int)fli, j0 = (int)flj, i1 = i0 + 1, j1 = j0 + 1;
      const float fi = ci - fli, fj = cj - flj, gi = 1.f - fi, gj = 1.f - fj;
      const bool bi0 = (unsigned)i0 < (unsigned)H, bi1 = (unsigned)i1 < (unsigned)H;
      const bool bj0 = (unsigned)j0 < (unsigned)W, bj1 = (unsigned)j1 < (unsigned)W;
      const int ic0 = min(max(i0, 0), H - 1), ic1 = min(max(i1, 0), H - 1);
      const int jc0 = min(max(j0, 0), W - 1), jc1 = min(max(j1, 0), W - 1);
      const float w00 = gi * gj * (float)(bi0 && bj0);
      const float w01 = gi * fj * (float)(bi0 && bj1);
      const float w10 = fi * gj * (float)(bi1 && bj0);
      const float w11 = fi * fj * (float)(bi1 && bj1);
      s_pw[wid][tap][pix][0] = bpack(w00, w01);
      s_pw[wid][tap][pix][1] = bpack(w10, w11);
      s_pa[wid][tap][pix][0] = (unsigned)(((b * H + ic0) * W + jc0) << 7);
      s_pa[wid][tap][pix][1] = (unsigned)(((b * H + ic0) * W + jc1) << 7);
      s_pa[wid][tap][pix][2] = (unsigned)(((b * H + ic1) * W + jc0) << 7);
      s_pa[wid][tap][pix][3] = (unsigned)(((b * H + ic1) * W + jc1) << 7);
    }
  }

  // gather lane map: 8 lanes (oct) cover one pixel-corner's 128B contiguously
  const int pix8 = l >> 3, oct = l & 7, cb = oct << 4;

  char* smb = (char*)s_m;
  const int wb  = ((wid * 16 + pix8) << 7) + ((oct ^ pix8) << 4);  // stage hs -> +hs*1024
  const int rr  = wid * 16 + (l & 15);
  const int rd0 = (rr << 7) + ((((l >> 4)    ) ^ (l & 7)) << 4);
  const int rd1 = (rr << 7) + (((4 + (l >> 4)) ^ (l & 7)) << 4);

  f32x4 acc[4];
#pragma unroll
  for (int mt = 0; mt < 4; ++mt) acc[mt] = (f32x4)0.f;

  uint4 g[2][4];   // 2-stage ring: stage hs covers px hs*8..hs*8+7, 4 corners
#define ISSUE(TAPX, HS) do {                                                   \
    const uint4 ad = *(const uint4*)&s_pa[wid][(TAPX)][(HS) * 8 + pix8][0];    \
    g[HS][0] = *(const uint4*)(xt + ad.x + cb);                                \
    g[HS][1] = *(const uint4*)(xt + ad.y + cb);                                \
    g[HS][2] = *(const uint4*)(xt + ad.z + cb);                                \
    g[HS][3] = *(const uint4*)(xt + ad.w + cb);                                \
  } while (0)

#define LERPB(w0_, w1_, w2_, w3_, c0_, c1_, c2_, c3_) bpack(                   \
    w0_ * lo16(c0_) + w1_ * lo16(c1_) + w2_ * lo16(c2_) + w3_ * lo16(c3_),     \
    w0_ * hi16(c0_) + w1_ * hi16(c1_) + w2_ * hi16(c2_) + w3_ * hi16(c3_))

#define STAGE(TAPV, HS) do {                                                   \
    const uint2 pk = *(const uint2*)&s_pw[wid][(TAPV)][(HS) * 8 + pix8][0];    \
    const float w0_ = lo16(pk.x), w1_ = hi16(pk.x);                            \
    const float w2_ = lo16(pk.y), w3_ = hi16(pk.y);                            \
    uint4* gc = g[HS];                                                         \
    uint4 r;                                                                   \
    r.x = LERPB(w0_, w1_, w2_, w3_, gc[0].x, gc[1].x, gc[2].x, gc[3].x);       \
    r.y = LERPB(w0_, w1_, w2_, w3_, gc[0].y, gc[1].y, gc[2].y, gc[3].y);       \
    r.z = LERPB(w0_, w1_, w2_, w3_, gc[0].z, gc[1].z, gc[2].z, gc[3].z);       \
    r.w = LERPB(w0_, w1_, w2_, w3_, gc[0].w, gc[1].w, gc[2].w, gc[3].w);       \
    *(uint4*)(smb + wb + (HS) * 1024) = r;                                     \
  } while (0)

  // prologue: stage tap 0's weights into buf 0, prefetch tap 0's gathers
  {
    const char* src = wfg + (size_t)t * 16;
    char* dst = (char*)s_wf + t * 16;
    gload16(src, dst);
    gload16(src + 4096, dst + 4096);
  }
  ISSUE(0, 0);
  ISSUE(0, 1);

#pragma unroll 1
  for (int tap = 0; tap < KK; ++tap) {
    __syncthreads();   // drains: wf buf[tap&1] ready, ring gathers ready, prev-buf reads done

    if (tap + 1 < KK) {            // stage next tap's weights into the other buffer
      const char* src = wfg + (size_t)(tap + 1) * 8192 + t * 16;
      char* dst = (char*)s_wf + ((tap + 1) & 1) * 8192 + t * 16;
      gload16(src, dst);
      gload16(src + 4096, dst + 4096);
    }

    STAGE(tap, 0);
    if (tap + 1 < KK) ISSUE(tap + 1, 0);
    STAGE(tap, 1);
    if (tap + 1 < KK) ISSUE(tap + 1, 1);

    // --- A from LDS wf buffer, B from s_m, 8 MFMA ---
    const char* wl = (const char*)s_wf + (tap & 1) * 8192;
    const s16x8 b0 = *(const s16x8*)(smb + rd0);
    const s16x8 b1 = *(const s16x8*)(smb + rd1);
#pragma unroll
    for (int mt = 0; mt < 4; ++mt) {
      const s16x8 a0 = *(const s16x8*)(wl + mt * 1024 + l * 16);
      acc[mt] = __builtin_amdgcn_mfma_f32_16x16x32_bf16(a0, b0, acc[mt], 0, 0, 0);
    }
#pragma unroll
    for (int mt = 0; mt < 4; ++mt) {
      const s16x8 a1 = *(const s16x8*)(wl + 4096 + mt * 1024 + l * 16);
      acc[mt] = __builtin_amdgcn_mfma_f32_16x16x32_bf16(a1, b1, acc[mt], 0, 0, 0);
    }
  }
#undef ISSUE
#undef LERPB
#undef STAGE

  // --- epilogue: coalesced stores (D: col=lane&15 -> pixel, row=(lane>>4)*4+j -> o) ---
#pragma unroll
  for (int mt = 0; mt < 4; ++mt)
#pragma unroll
    for (int j = 0; j < 4; ++j) {
      const int o = mt * 16 + ((l >> 4) << 2) + j;
      out[((size_t)(b * O + o) * H + h) * W + wbase + (l & 15)] = acc[mt][j];
    }
}

// ---------- fallback (round-1 kernel, used only if ws too small) ----------
namespace fb {
constexpr int WT = 32, CH = 16, NCHUNK = 4, KC = 144, WPAD = 68;
}
__global__ __launch_bounds__(PREPT, 2)
void deform_conv_fused(const float* __restrict__ x, const float* __restrict__ offs,
                       const float* __restrict__ wgt, float* __restrict__ out) {
  using namespace fb;
  __shared__ int   s_i0[KK][WT];
  __shared__ int   s_j0[KK][WT];
  __shared__ float s_fi[KK][WT];
  __shared__ float s_fj[KK][WT];
  __shared__ float s_w[KC][WPAD];
  __shared__ float s_m[KC][WT + 1];
  const int t = threadIdx.x;
  const int nwt = W / WT;
  const int wt = blockIdx.x % nwt, h = (blockIdx.x / nwt) % H, b = blockIdx.x / (nwt * H);
  const int w0 = wt * WT;
  for (int idx = t; idx < KK * WT; idx += PREPT) {
    const int k = idx / WT, p = idx % WT, w = w0 + p;
    const float oi = offs[(((size_t)b * (2 * KK) + 2 * k) * H + h) * W + w];
    const float oj = offs[(((size_t)b * (2 * KK) + 2 * k + 1) * H + h) * W + w];
    const float ci = oi + (float)(h + (k / 3) - 1), cj = oj + (float)(w + (k % 3) - 1);
    const float fli = floorf(ci), flj = floorf(cj);
    s_i0[k][p] = (int)fli; s_j0[k][p] = (int)flj;
    s_fi[k][p] = ci - fli; s_fj[k][p] = cj - flj;
  }
  float acc[8];
#pragma unroll
  for (int i = 0; i < 8; ++i) acc[i] = 0.f;
  const int p = t & (WT - 1), ob = (t >> 5) * 8;
  for (int cc = 0; cc < NCHUNK; ++cc) {
    const int c0 = cc * CH;
    __syncthreads();
    for (int idx = t; idx < O * KC; idx += PREPT)
      s_w[idx % KC][idx / KC] = wgt[(size_t)(idx / KC) * (C * KK) + (size_t)c0 * KK + idx % KC];
    for (int idx = t; idx < CH * KK * WT; idx += PREPT) {
      const int pp = idx & (WT - 1), rest = idx >> 5, k = rest % KK, cl = rest / KK;
      const int i0 = s_i0[k][pp], j0 = s_j0[k][pp], i1 = i0 + 1, j1 = j0 + 1;
      const float fi = s_fi[k][pp], fj = s_fj[k][pp];
      const float* xb = x + (size_t)(b * C + c0 + cl) * H * W;
      const float v00 = ((unsigned)i0 < (unsigned)H && (unsigned)j0 < (unsigned)W) ? xb[i0 * W + j0] : 0.f;
      const float v01 = ((unsigned)i0 < (unsigned)H && (unsigned)j1 < (unsigned)W) ? xb[i0 * W + j1] : 0.f;
      const float v10 = ((unsigned)i1 < (unsigned)H && (unsigned)j0 < (unsigned)W) ? xb[i1 * W + j0] : 0.f;
      const float v11 = ((unsigned)i1 < (unsigned)H && (unsigned)j1 < (unsigned)W) ? xb[i1 * W + j1] : 0.f;
      const float top = v00 + fj * (v01 - v00), bot = v10 + fj * (v11 - v10);
      s_m[cl * KK + k][pp] = top + fi * (bot - top);
    }
    __syncthreads();
#pragma unroll 4
    for (int k = 0; k < KC; ++k) {
      const float a = s_m[k][p];
      const float4 wv0 = *reinterpret_cast<const float4*>(&s_w[k][ob]);
      const float4 wv1 = *reinterpret_cast<const float4*>(&s_w[k][ob + 4]);
      acc[0] += a * wv0.x; acc[1] += a * wv0.y; acc[2] += a * wv0.z; acc[3] += a * wv0.w;
      acc[4] += a * wv1.x; acc[5] += a * wv1.y; acc[6] += a * wv1.z; acc[7] += a * wv1.w;
    }
  }
#pragma unroll
  for (int i = 0; i < 8; ++i)
    out[(((size_t)b * O + ob + i) * H + h) * W + w0 + p] = acc[i];
}

extern "C" void kernel_launch(void* const* d_in, const int* in_sizes, int n_in,
                              void* d_out, int out_size, void* d_ws, size_t ws_size,
                              hipStream_t stream) {
  const float* x    = (const float*)d_in[0];
  const float* offs = (const float*)d_in[1];
  const float* wgt  = (const float*)d_in[2];
  float* out = (float*)d_out;

  if (ws_size < WS_NEED) {   // fallback: round-1 kernel
    deform_conv_fused<<<B * H * (W / 32), PREPT, 0, stream>>>(x, offs, wgt, out);
    return;
  }
  char* xt = (char*)d_ws;
  unsigned short* wf = (unsigned short*)(xt + XT_BYTES);

  prep_fused<<<B * H * 2, PREPT, 0, stream>>>(x, wgt, (unsigned*)xt, wf);
  deform_mfma<<<B * H * 2, 256, 0, stream>>>(offs, xt, (const char*)wf, out);
}